// Round 3
// baseline (1393.198 us; speedup 1.0000x reference)
//
#include <hip/hip_runtime.h>
#include <math.h>

typedef __attribute__((ext_vector_type(8))) short bf16x8;
typedef __attribute__((ext_vector_type(4))) float f32x4;
typedef __attribute__((ext_vector_type(4))) unsigned int u32x4;
typedef __attribute__((ext_vector_type(4))) unsigned short u16x4;

static constexpr int Tn = 2048;
static constexpr int Dm = 256;
static constexpr int NHn = 4;
static constexpr int Ln = 4;
static constexpr int DFFn = 1024;
static constexpr int Vn = 32000;
static constexpr int BTn = 4096;   // B*T

__device__ __forceinline__ unsigned short f2bf(float f) {
  unsigned int u = __float_as_uint(f);
  u += 0x7fffu + ((u >> 16) & 1u);
  return (unsigned short)(u >> 16);
}

// ---------------- merged fp32 -> bf16 convert for all 5 weight tensors ----------------
__global__ __launch_bounds__(256) void cvt_all(const float* __restrict__ s0, unsigned short* __restrict__ d0,
                                               const float* __restrict__ s1, unsigned short* __restrict__ d1,
                                               const float* __restrict__ s2, unsigned short* __restrict__ d2,
                                               const float* __restrict__ s3, unsigned short* __restrict__ d3,
                                               const float* __restrict__ s4, unsigned short* __restrict__ d4,
                                               int e0, int e1, int e2, int e3, int e4) {
  int g = blockIdx.x * 256 + threadIdx.x;   // vec4 index
  if (g >= e4) return;
  const float* s; unsigned short* d; int base;
  if (g < e0)      { s = s0; d = d0; base = 0; }
  else if (g < e1) { s = s1; d = d1; base = e0; }
  else if (g < e2) { s = s2; d = d2; base = e1; }
  else if (g < e3) { s = s3; d = d3; base = e2; }
  else             { s = s4; d = d4; base = e3; }
  int i = (g - base) * 4;
  float4 v = *reinterpret_cast<const float4*>(s + i);
  u16x4 o;
  o[0] = f2bf(v.x); o[1] = f2bf(v.y); o[2] = f2bf(v.z); o[3] = f2bf(v.w);
  *reinterpret_cast<u16x4*>(d + i) = o;
}

// ---------------- embedding + positional encoding ----------------
__global__ __launch_bounds__(256) void embed_pos(const int* __restrict__ tokens,
                                                 const float* __restrict__ emb,
                                                 float* __restrict__ xf,
                                                 unsigned short* __restrict__ xb) {
  int idx = blockIdx.x * 256 + threadIdx.x;   // BTn*Dm total
  int bt = idx >> 8, d = idx & 255;
  int t = bt & (Tn - 1);
  int tok = tokens[bt];
  float v = emb[(size_t)tok * Dm + d];
  int i2 = d & ~1;
  float dv = expf((float)i2 * (-0.03597789207803249f));  // -ln(10000)/256
  float arg = (float)t * dv;
  float pe = (d & 1) ? cosf(arg) : sinf(arg);
  float x = v + pe;
  xf[idx] = x;
  xb[idx] = f2bf(x);
}

// ---------------- (optional add) + layernorm; writes fp32 + bf16 shadow ----------------
__global__ __launch_bounds__(256) void add_ln(const float* __restrict__ addend,
                                              const float* __restrict__ gam,
                                              const float* __restrict__ bet,
                                              float* __restrict__ xf,
                                              unsigned short* __restrict__ xb) {
  int row = blockIdx.x, d = threadIdx.x;   // 256 threads = D
  __shared__ float red[8];
  size_t off = (size_t)row * Dm + d;
  float u = xf[off];
  if (addend) u += addend[off];
  float tsum = u;
  #pragma unroll
  for (int o = 32; o > 0; o >>= 1) tsum += __shfl_xor(tsum, o);
  int w = d >> 6, lane = d & 63;
  if (lane == 0) red[w] = tsum;
  __syncthreads();
  float mean = (red[0] + red[1] + red[2] + red[3]) * (1.f / 256.f);
  float df = u - mean;
  float vsum = df * df;
  #pragma unroll
  for (int o = 32; o > 0; o >>= 1) vsum += __shfl_xor(vsum, o);
  if (lane == 0) red[4 + w] = vsum;
  __syncthreads();
  float var = (red[4] + red[5] + red[6] + red[7]) * (1.f / 256.f);
  float y = df * rsqrtf(var + 1e-5f) * gam[d] + bet[d];
  xf[off] = y;
  xb[off] = f2bf(y);
}

// ---------------- bf16 MFMA flash attention (causal) ----------------
// qkv bf16 layout per row (bt): [q(0:256) | k(256:512) | v(512:768)], within each: h*64+dk
// Block: 64 q-rows, 4 waves x 16 rows. KV tile = 64.
__global__ __launch_bounds__(256) void attn_mfma(const unsigned short* __restrict__ qkv,
                                                 unsigned short* __restrict__ ob) {
  // XCD-chunked remap: grid (32, 8); each XCD gets one (b,h) -> K/V L2-resident
  int lin = blockIdx.y * gridDim.x + blockIdx.x;
  int wg = (lin & 7) * 32 + (lin >> 3);
  int qb = wg & 31, bh = wg >> 5;
  int b = bh >> 2, h = bh & 3;       // H=4
  int q0 = qb * 64;
  int tid = threadIdx.x;
  int lane = tid & 63, w = tid >> 6;
  int l15 = lane & 15, quad = lane >> 4;

  // XOR-swizzled LDS: byte ^= (row&7)<<4 within 128B rows -> conflict-free b128 reads
  __shared__ __align__(16) unsigned short Ps[4][16 * 64];  // per-wave P[q][kv]
  __shared__ __align__(16) unsigned short Vt[64 * 64];     // V^T[dk][kv], shared

  // Q A-fragments, loaded once from global (row = q, k = feature)
  const size_t rowQ = (size_t)(b * Tn + q0 + w * 16 + l15) * 768 + h * 64 + quad * 8;
  bf16x8 aq0 = *reinterpret_cast<const bf16x8*>(qkv + rowQ);
  bf16x8 aq1 = *reinterpret_cast<const bf16x8*>(qkv + rowQ + 32);

  float m_i[4], l_i[4];
  f32x4 oacc[4];
  #pragma unroll
  for (int i = 0; i < 4; i++) { m_i[i] = -INFINITY; l_i[i] = 0.f; oacc[i] = (f32x4){0.f, 0.f, 0.f, 0.f}; }

  for (int jt = 0; jt <= qb; jt++) {
    int j0 = jt * 64;
    __syncthreads();   // protect Vt from previous tile's readers
    // ---- stage V^T into swizzled LDS ----
    {
      int kv = tid & 63, g = tid >> 6;   // each wave stages 16 dk rows
      const unsigned short* vsrc = qkv + (size_t)(b * Tn + j0 + kv) * 768 + 512 + h * 64 + g * 16;
      bf16x8 v0 = *reinterpret_cast<const bf16x8*>(vsrc);
      bf16x8 v1 = *reinterpret_cast<const bf16x8*>(vsrc + 8);
      char* vb = (char*)Vt;
      #pragma unroll
      for (int j = 0; j < 8; j++) {
        int dk = g * 16 + j;
        *(unsigned short*)(vb + (((dk * 128 + kv * 2)) ^ ((dk & 7) << 4))) = (unsigned short)v0[j];
      }
      #pragma unroll
      for (int j = 0; j < 8; j++) {
        int dk = g * 16 + 8 + j;
        *(unsigned short*)(vb + (((dk * 128 + kv * 2)) ^ ((dk & 7) << 4))) = (unsigned short)v1[j];
      }
    }
    __syncthreads();

    // ---- S = Q K^T : K B-frags direct from global (L2-resident) ----
    f32x4 sc[4];
    const size_t rowK = (size_t)(b * Tn + j0 + l15) * 768 + 256 + h * 64 + quad * 8;
    #pragma unroll
    for (int f = 0; f < 4; f++) {
      bf16x8 bk0 = *reinterpret_cast<const bf16x8*>(qkv + rowK + (size_t)f * 16 * 768);
      bf16x8 bk1 = *reinterpret_cast<const bf16x8*>(qkv + rowK + (size_t)f * 16 * 768 + 32);
      f32x4 a = (f32x4){0.f, 0.f, 0.f, 0.f};
      a = __builtin_amdgcn_mfma_f32_16x16x32_bf16(aq0, bk0, a, 0, 0, 0);
      a = __builtin_amdgcn_mfma_f32_16x16x32_bf16(aq1, bk1, a, 0, 0, 0);
      sc[f] = a;
    }

    // ---- online softmax ----
    bool diag = (jt == qb);
    float alpha[4];
    #pragma unroll
    for (int rr = 0; rr < 4; rr++) {
      int qg = q0 + w * 16 + quad * 4 + rr;
      float sv[4];
      #pragma unroll
      for (int f = 0; f < 4; f++) {
        sv[f] = sc[f][rr] * 0.125f;
        if (diag && (j0 + f * 16 + l15 > qg)) sv[f] = -INFINITY;
      }
      float mx = fmaxf(fmaxf(sv[0], sv[1]), fmaxf(sv[2], sv[3]));
      #pragma unroll
      for (int o = 8; o > 0; o >>= 1) mx = fmaxf(mx, __shfl_xor(mx, o));
      float mnew = fmaxf(m_i[rr], mx);
      float p[4], ps = 0.f;
      #pragma unroll
      for (int f = 0; f < 4; f++) { p[f] = __expf(sv[f] - mnew); ps += p[f]; }
      #pragma unroll
      for (int o = 8; o > 0; o >>= 1) ps += __shfl_xor(ps, o);
      alpha[rr] = __expf(m_i[rr] - mnew);   // first tile: exp(-inf) = 0
      l_i[rr] = l_i[rr] * alpha[rr] + ps;
      m_i[rr] = mnew;
      int qq = quad * 4 + rr;
      char* pb = (char*)Ps[w];
      #pragma unroll
      for (int f = 0; f < 4; f++)
        *(unsigned short*)(pb + (((qq * 128 + (f * 16 + l15) * 2)) ^ ((qq & 7) << 4))) = f2bf(p[f]);
    }

    // ---- rescale O ----
    #pragma unroll
    for (int ni = 0; ni < 4; ni++)
      #pragma unroll
      for (int rr = 0; rr < 4; rr++) oacc[ni][rr] *= alpha[rr];

    // ---- O += P V ----
    bf16x8 pa[2];
    {
      char* pb = (char*)Ps[w];
      #pragma unroll
      for (int kc = 0; kc < 2; kc++)
        pa[kc] = *reinterpret_cast<const bf16x8*>(
            pb + (((l15 * 128 + kc * 64 + quad * 16)) ^ ((l15 & 7) << 4)));
    }
    char* vb = (char*)Vt;
    #pragma unroll
    for (int ni = 0; ni < 4; ni++) {
      int dk = ni * 16 + l15;
      #pragma unroll
      for (int kc = 0; kc < 2; kc++) {
        bf16x8 bv = *reinterpret_cast<const bf16x8*>(
            vb + (((dk * 128 + kc * 64 + quad * 16)) ^ ((dk & 7) << 4)));
        oacc[ni] = __builtin_amdgcn_mfma_f32_16x16x32_bf16(pa[kc], bv, oacc[ni], 0, 0, 0);
      }
    }
  }

  // ---- epilogue: O / l, write bf16 ----
  #pragma unroll
  for (int ni = 0; ni < 4; ni++) {
    #pragma unroll
    for (int rr = 0; rr < 4; rr++) {
      int qg = q0 + w * 16 + quad * 4 + rr;
      float o = oacc[ni][rr] / l_i[rr];
      ob[(size_t)(b * Tn + qg) * Dm + h * 64 + ni * 16 + l15] = f2bf(o);
    }
  }
}

// ---------------- bf16 MFMA GEMM, register-file only (no LDS, no barriers) ----------------
// C[M,N] = A[M,K] * W[N,K]^T + bias. All operands L2-resident; waves load MFMA
// fragments directly from global (16B/lane). K templated for full unroll.
// Grid: x = M/BM (inner), y = N/128. XCD-bijective remap, M innermost.
// EPI 0: fp32 out.  EPI 1: bf16(relu(out)).  EPI 2: bf16(out).
template <int BM, int K, int EPI>
__global__ __launch_bounds__(256) void gemm_rf(const unsigned short* __restrict__ A,
                                               const unsigned short* __restrict__ W,
                                               const float* __restrict__ bias,
                                               float* __restrict__ Cf,
                                               unsigned short* __restrict__ Cb,
                                               int N) {
  constexpr int MI = BM / 32;                      // A-frags per wave
  int tid = threadIdx.x;
  int lane = tid & 63, w = tid >> 6;
  int wm = (w >> 1) * (BM / 2), wn = (w & 1) * 64;
  int r = lane & 15, quad = lane >> 4;

  // XCD-aware bijective remap (m204), M innermost: consecutive wg on one XCD
  // share the same B panel (L2-hot) and walk M (A panel L2-hot).
  int gx = gridDim.x;
  int nwg = gx * gridDim.y;
  int lin = blockIdx.y * gx + blockIdx.x;
  int xcd = lin & 7, pos = lin >> 3;
  int qch = nwg >> 3, rch = nwg & 7;
  int wg = (xcd < rch ? xcd * (qch + 1) : rch * (qch + 1) + (xcd - rch) * qch) + pos;
  int m0 = (wg % gx) * BM;
  int n0 = (wg / gx) * 128;

  const unsigned short* Ap = A + (size_t)(m0 + wm + r) * K + quad * 8;
  const unsigned short* Wp = W + (size_t)(n0 + wn + r) * K + quad * 8;

  f32x4 acc[MI][4];
  #pragma unroll
  for (int i = 0; i < MI; i++)
    #pragma unroll
    for (int j = 0; j < 4; j++) acc[i][j] = (f32x4){0.f, 0.f, 0.f, 0.f};

  #pragma unroll 8
  for (int k0 = 0; k0 < K; k0 += 32) {
    bf16x8 af[MI], bfr[4];
    #pragma unroll
    for (int mi = 0; mi < MI; mi++)
      af[mi] = *reinterpret_cast<const bf16x8*>(Ap + (size_t)mi * 16 * K + k0);
    #pragma unroll
    for (int ni = 0; ni < 4; ni++)
      bfr[ni] = *reinterpret_cast<const bf16x8*>(Wp + (size_t)ni * 16 * K + k0);
    #pragma unroll
    for (int mi = 0; mi < MI; mi++)
      #pragma unroll
      for (int ni = 0; ni < 4; ni++)
        acc[mi][ni] = __builtin_amdgcn_mfma_f32_16x16x32_bf16(af[mi], bfr[ni], acc[mi][ni], 0, 0, 0);
  }

  #pragma unroll
  for (int mi = 0; mi < MI; mi++) {
    #pragma unroll
    for (int ni = 0; ni < 4; ni++) {
      int n = n0 + wn + ni * 16 + r;          // C/D: col = lane&15
      float bv = bias[n];
      #pragma unroll
      for (int rr = 0; rr < 4; rr++) {
        int m = m0 + wm + mi * 16 + quad * 4 + rr;   // C/D: row = quad*4+reg
        float v = acc[mi][ni][rr] + bv;
        if (EPI == 0) {
          Cf[(size_t)m * N + n] = v;
        } else if (EPI == 1) {
          Cb[(size_t)m * N + n] = f2bf(fmaxf(v, 0.f));
        } else {
          Cb[(size_t)m * N + n] = f2bf(v);
        }
      }
    }
  }
}

extern "C" void kernel_launch(void* const* d_in, const int* in_sizes, int n_in,
                              void* d_out, int out_size, void* d_ws, size_t ws_size,
                              hipStream_t stream) {
  (void)in_sizes; (void)n_in; (void)out_size; (void)ws_size;
  const int* tokens = (const int*)d_in[0];
  const float* emb = (const float*)d_in[1];
  const float* qkv_w = (const float*)d_in[2];
  const float* qkv_b = (const float*)d_in[3];
  const float* fc_w = (const float*)d_in[4];
  const float* fc_b = (const float*)d_in[5];
  const float* ln1_s = (const float*)d_in[6];
  const float* ln1_b = (const float*)d_in[7];
  const float* w1 = (const float*)d_in[8];
  const float* b1 = (const float*)d_in[9];
  const float* w2 = (const float*)d_in[10];
  const float* b2 = (const float*)d_in[11];
  const float* ln2_s = (const float*)d_in[12];
  const float* ln2_b = (const float*)d_in[13];
  const float* lnf_s = (const float*)d_in[14];
  const float* lnf_b = (const float*)d_in[15];
  const float* out_w = (const float*)d_in[16];
  const float* out_b = (const float*)d_in[17];
  float* logits = (float*)d_out;

  char* p = (char*)d_ws;
  auto carve = [&](size_t bytes) {
    char* r = p;
    p += (bytes + 255) & ~(size_t)255;
    return r;
  };
  float* xf = (float*)carve((size_t)BTn * Dm * 4);
  unsigned short* xb = (unsigned short*)carve((size_t)BTn * Dm * 2);
  unsigned short* qkvb = (unsigned short*)carve((size_t)BTn * 768 * 2);
  unsigned short* obb = (unsigned short*)carve((size_t)BTn * Dm * 2);
  float* of = (float*)carve((size_t)BTn * Dm * 4);
  unsigned short* hb = (unsigned short*)carve((size_t)BTn * DFFn * 2);
  float* ff = (float*)carve((size_t)BTn * Dm * 4);
  unsigned short* wqkvb = (unsigned short*)carve((size_t)Ln * 768 * Dm * 2);
  unsigned short* wfcb = (unsigned short*)carve((size_t)Ln * Dm * Dm * 2);
  unsigned short* w1b = (unsigned short*)carve((size_t)Ln * DFFn * Dm * 2);
  unsigned short* w2b = (unsigned short*)carve((size_t)Ln * Dm * DFFn * 2);
  unsigned short* outwb = (unsigned short*)carve((size_t)Vn * Dm * 2);

  // merged weight conversion (5 tensors, one launch); offsets in vec4 units
  {
    int c0 = Ln * 768 * Dm / 4;
    int c1 = c0 + Ln * Dm * Dm / 4;
    int c2 = c1 + Ln * DFFn * Dm / 4;
    int c3 = c2 + Ln * Dm * DFFn / 4;
    int c4 = c3 + Vn * Dm / 4;
    cvt_all<<<dim3((c4 + 255) / 256), dim3(256), 0, stream>>>(
        qkv_w, wqkvb, fc_w, wfcb, w1, w1b, w2, w2b, out_w, outwb, c0, c1, c2, c3, c4);
  }

  embed_pos<<<dim3(BTn), dim3(256), 0, stream>>>(tokens, emb, xf, xb);

  for (int l = 0; l < Ln; l++) {
    gemm_rf<64, 256, 2><<<dim3(BTn / 64, 768 / 128), dim3(256), 0, stream>>>(
        xb, wqkvb + (size_t)l * 768 * Dm, qkv_b + l * 768, nullptr, qkvb, 768);
    attn_mfma<<<dim3(Tn / 64, 2 * NHn), dim3(256), 0, stream>>>(qkvb, obb);
    gemm_rf<32, 256, 0><<<dim3(BTn / 32, Dm / 128), dim3(256), 0, stream>>>(
        obb, wfcb + (size_t)l * Dm * Dm, fc_b + l * Dm, of, nullptr, Dm);
    add_ln<<<dim3(BTn), dim3(256), 0, stream>>>(of, ln1_s + l * Dm, ln1_b + l * Dm, xf, xb);
    gemm_rf<64, 256, 1><<<dim3(BTn / 64, DFFn / 128), dim3(256), 0, stream>>>(
        xb, w1b + (size_t)l * DFFn * Dm, b1 + l * DFFn, nullptr, hb, DFFn);
    gemm_rf<32, 1024, 0><<<dim3(BTn / 32, Dm / 128), dim3(256), 0, stream>>>(
        hb, w2b + (size_t)l * Dm * DFFn, b2 + l * Dm, ff, nullptr, Dm);
    add_ln<<<dim3(BTn), dim3(256), 0, stream>>>(ff, ln2_s + l * Dm, ln2_b + l * Dm, xf, xb);
  }
  add_ln<<<dim3(BTn), dim3(256), 0, stream>>>(nullptr, lnf_s, lnf_b, xf, xb);

  gemm_rf<128, 256, 0><<<dim3(BTn / 128, Vn / 128), dim3(256), 0, stream>>>(
      xb, outwb, out_b, logits, nullptr, Vn);
}

// Round 4
// 1204.026 us; speedup vs baseline: 1.1571x; 1.1571x over previous
//
#include <hip/hip_runtime.h>
#include <math.h>

typedef __attribute__((ext_vector_type(8))) short bf16x8;
typedef __attribute__((ext_vector_type(4))) float f32x4;
typedef __attribute__((ext_vector_type(4))) unsigned int u32x4;
typedef __attribute__((ext_vector_type(4))) unsigned short u16x4;

static constexpr int Tn = 2048;
static constexpr int Dm = 256;
static constexpr int NHn = 4;
static constexpr int Ln = 4;
static constexpr int DFFn = 1024;
static constexpr int Vn = 32000;
static constexpr int BTn = 4096;   // B*T

__device__ __forceinline__ unsigned short f2bf(float f) {
  unsigned int u = __float_as_uint(f);
  u += 0x7fffu + ((u >> 16) & 1u);
  return (unsigned short)(u >> 16);
}

// async global->LDS, 16B per lane; LDS dest wave-uniform (HW adds lane*16)
__device__ __forceinline__ void gld_lds16(const unsigned short* g, unsigned short* l) {
  __builtin_amdgcn_global_load_lds((const __attribute__((address_space(1))) unsigned int*)g,
                                   (__attribute__((address_space(3))) unsigned int*)l, 16, 0, 0);
}

// ---------------- merged fp32 -> bf16 convert for all 5 weight tensors ----------------
__global__ __launch_bounds__(256) void cvt_all(const float* __restrict__ s0, unsigned short* __restrict__ d0,
                                               const float* __restrict__ s1, unsigned short* __restrict__ d1,
                                               const float* __restrict__ s2, unsigned short* __restrict__ d2,
                                               const float* __restrict__ s3, unsigned short* __restrict__ d3,
                                               const float* __restrict__ s4, unsigned short* __restrict__ d4,
                                               int e0, int e1, int e2, int e3, int e4) {
  int g = blockIdx.x * 256 + threadIdx.x;   // vec4 index
  if (g >= e4) return;
  const float* s; unsigned short* d; int base;
  if (g < e0)      { s = s0; d = d0; base = 0; }
  else if (g < e1) { s = s1; d = d1; base = e0; }
  else if (g < e2) { s = s2; d = d2; base = e1; }
  else if (g < e3) { s = s3; d = d3; base = e2; }
  else             { s = s4; d = d4; base = e3; }
  int i = (g - base) * 4;
  float4 v = *reinterpret_cast<const float4*>(s + i);
  u16x4 o;
  o[0] = f2bf(v.x); o[1] = f2bf(v.y); o[2] = f2bf(v.z); o[3] = f2bf(v.w);
  *reinterpret_cast<u16x4*>(d + i) = o;
}

// ---------------- embedding + positional encoding ----------------
__global__ __launch_bounds__(256) void embed_pos(const int* __restrict__ tokens,
                                                 const float* __restrict__ emb,
                                                 float* __restrict__ xf,
                                                 unsigned short* __restrict__ xb) {
  int idx = blockIdx.x * 256 + threadIdx.x;   // BTn*Dm total
  int bt = idx >> 8, d = idx & 255;
  int t = bt & (Tn - 1);
  int tok = tokens[bt];
  float v = emb[(size_t)tok * Dm + d];
  int i2 = d & ~1;
  float dv = expf((float)i2 * (-0.03597789207803249f));  // -ln(10000)/256
  float arg = (float)t * dv;
  float pe = (d & 1) ? cosf(arg) : sinf(arg);
  float x = v + pe;
  xf[idx] = x;
  xb[idx] = f2bf(x);
}

// ---------------- final layernorm (standalone) ----------------
__global__ __launch_bounds__(256) void add_ln(const float* __restrict__ addend,
                                              const float* __restrict__ gam,
                                              const float* __restrict__ bet,
                                              float* __restrict__ xf,
                                              unsigned short* __restrict__ xb) {
  int row = blockIdx.x, d = threadIdx.x;   // 256 threads = D
  __shared__ float red[8];
  size_t off = (size_t)row * Dm + d;
  float u = xf[off];
  if (addend) u += addend[off];
  float tsum = u;
  #pragma unroll
  for (int o = 32; o > 0; o >>= 1) tsum += __shfl_xor(tsum, o);
  int w = d >> 6, lane = d & 63;
  if (lane == 0) red[w] = tsum;
  __syncthreads();
  float mean = (red[0] + red[1] + red[2] + red[3]) * (1.f / 256.f);
  float df = u - mean;
  float vsum = df * df;
  #pragma unroll
  for (int o = 32; o > 0; o >>= 1) vsum += __shfl_xor(vsum, o);
  if (lane == 0) red[4 + w] = vsum;
  __syncthreads();
  float var = (red[4] + red[5] + red[6] + red[7]) * (1.f / 256.f);
  float y = df * rsqrtf(var + 1e-5f) * gam[d] + bet[d];
  xf[off] = y;
  xb[off] = f2bf(y);
}

// ---------------- bf16 MFMA flash attention (causal) ----------------
// qkv bf16 layout per row (bt): [q(0:256) | k(256:512) | v(512:768)], within each: h*64+dk
// Block: 64 q-rows, 4 waves x 16 rows. KV tile = 64.
__global__ __launch_bounds__(256) void attn_mfma(const unsigned short* __restrict__ qkv,
                                                 unsigned short* __restrict__ ob) {
  // XCD-chunked remap: grid (32, 8); each XCD gets one (b,h) -> K/V L2-resident
  int lin = blockIdx.y * gridDim.x + blockIdx.x;
  int wg = (lin & 7) * 32 + (lin >> 3);
  int qb = wg & 31, bh = wg >> 5;
  int b = bh >> 2, h = bh & 3;       // H=4
  int q0 = qb * 64;
  int tid = threadIdx.x;
  int lane = tid & 63, w = tid >> 6;
  int l15 = lane & 15, quad = lane >> 4;

  // XOR-swizzled LDS: byte ^= (row&7)<<4 within 128B rows -> conflict-free b128 reads
  __shared__ __align__(16) unsigned short Ps[4][16 * 64];  // per-wave P[q][kv]
  __shared__ __align__(16) unsigned short Vt[64 * 64];     // V^T[dk][kv], shared

  // Q A-fragments, loaded once from global (row = q, k = feature)
  const size_t rowQ = (size_t)(b * Tn + q0 + w * 16 + l15) * 768 + h * 64 + quad * 8;
  bf16x8 aq0 = *reinterpret_cast<const bf16x8*>(qkv + rowQ);
  bf16x8 aq1 = *reinterpret_cast<const bf16x8*>(qkv + rowQ + 32);

  float m_i[4], l_i[4];
  f32x4 oacc[4];
  #pragma unroll
  for (int i = 0; i < 4; i++) { m_i[i] = -INFINITY; l_i[i] = 0.f; oacc[i] = (f32x4){0.f, 0.f, 0.f, 0.f}; }

  for (int jt = 0; jt <= qb; jt++) {
    int j0 = jt * 64;
    __syncthreads();   // protect Vt from previous tile's readers
    // ---- stage V^T into swizzled LDS ----
    {
      int kv = tid & 63, g = tid >> 6;   // each wave stages 16 dk rows
      const unsigned short* vsrc = qkv + (size_t)(b * Tn + j0 + kv) * 768 + 512 + h * 64 + g * 16;
      bf16x8 v0 = *reinterpret_cast<const bf16x8*>(vsrc);
      bf16x8 v1 = *reinterpret_cast<const bf16x8*>(vsrc + 8);
      char* vb = (char*)Vt;
      #pragma unroll
      for (int j = 0; j < 8; j++) {
        int dk = g * 16 + j;
        *(unsigned short*)(vb + (((dk * 128 + kv * 2)) ^ ((dk & 7) << 4))) = (unsigned short)v0[j];
      }
      #pragma unroll
      for (int j = 0; j < 8; j++) {
        int dk = g * 16 + 8 + j;
        *(unsigned short*)(vb + (((dk * 128 + kv * 2)) ^ ((dk & 7) << 4))) = (unsigned short)v1[j];
      }
    }
    __syncthreads();

    // ---- S = Q K^T : K B-frags direct from global (L2-resident) ----
    f32x4 sc[4];
    const size_t rowK = (size_t)(b * Tn + j0 + l15) * 768 + 256 + h * 64 + quad * 8;
    #pragma unroll
    for (int f = 0; f < 4; f++) {
      bf16x8 bk0 = *reinterpret_cast<const bf16x8*>(qkv + rowK + (size_t)f * 16 * 768);
      bf16x8 bk1 = *reinterpret_cast<const bf16x8*>(qkv + rowK + (size_t)f * 16 * 768 + 32);
      f32x4 a = (f32x4){0.f, 0.f, 0.f, 0.f};
      a = __builtin_amdgcn_mfma_f32_16x16x32_bf16(aq0, bk0, a, 0, 0, 0);
      a = __builtin_amdgcn_mfma_f32_16x16x32_bf16(aq1, bk1, a, 0, 0, 0);
      sc[f] = a;
    }

    // ---- online softmax ----
    bool diag = (jt == qb);
    float alpha[4];
    #pragma unroll
    for (int rr = 0; rr < 4; rr++) {
      int qg = q0 + w * 16 + quad * 4 + rr;
      float sv[4];
      #pragma unroll
      for (int f = 0; f < 4; f++) {
        sv[f] = sc[f][rr] * 0.125f;
        if (diag && (j0 + f * 16 + l15 > qg)) sv[f] = -INFINITY;
      }
      float mx = fmaxf(fmaxf(sv[0], sv[1]), fmaxf(sv[2], sv[3]));
      #pragma unroll
      for (int o = 8; o > 0; o >>= 1) mx = fmaxf(mx, __shfl_xor(mx, o));
      float mnew = fmaxf(m_i[rr], mx);
      float p[4], ps = 0.f;
      #pragma unroll
      for (int f = 0; f < 4; f++) { p[f] = __expf(sv[f] - mnew); ps += p[f]; }
      #pragma unroll
      for (int o = 8; o > 0; o >>= 1) ps += __shfl_xor(ps, o);
      alpha[rr] = __expf(m_i[rr] - mnew);   // first tile: exp(-inf) = 0
      l_i[rr] = l_i[rr] * alpha[rr] + ps;
      m_i[rr] = mnew;
      int qq = quad * 4 + rr;
      char* pb = (char*)Ps[w];
      #pragma unroll
      for (int f = 0; f < 4; f++)
        *(unsigned short*)(pb + (((qq * 128 + (f * 16 + l15) * 2)) ^ ((qq & 7) << 4))) = f2bf(p[f]);
    }

    // ---- rescale O ----
    #pragma unroll
    for (int ni = 0; ni < 4; ni++)
      #pragma unroll
      for (int rr = 0; rr < 4; rr++) oacc[ni][rr] *= alpha[rr];

    // ---- O += P V ----
    bf16x8 pa[2];
    {
      char* pb = (char*)Ps[w];
      #pragma unroll
      for (int kc = 0; kc < 2; kc++)
        pa[kc] = *reinterpret_cast<const bf16x8*>(
            pb + (((l15 * 128 + kc * 64 + quad * 16)) ^ ((l15 & 7) << 4)));
    }
    char* vb = (char*)Vt;
    #pragma unroll
    for (int ni = 0; ni < 4; ni++) {
      int dk = ni * 16 + l15;
      #pragma unroll
      for (int kc = 0; kc < 2; kc++) {
        bf16x8 bv = *reinterpret_cast<const bf16x8*>(
            vb + (((dk * 128 + kc * 64 + quad * 16)) ^ ((dk & 7) << 4)));
        oacc[ni] = __builtin_amdgcn_mfma_f32_16x16x32_bf16(pa[kc], bv, oacc[ni], 0, 0, 0);
      }
    }
  }

  // ---- epilogue: O / l, write bf16 ----
  #pragma unroll
  for (int ni = 0; ni < 4; ni++) {
    #pragma unroll
    for (int rr = 0; rr < 4; rr++) {
      int qg = q0 + w * 16 + quad * 4 + rr;
      float o = oacc[ni][rr] / l_i[rr];
      ob[(size_t)(b * Tn + qg) * Dm + h * 64 + ni * 16 + l15] = f2bf(o);
    }
  }
}

// ---------------- bf16 MFMA GEMM, gload_lds + 2-phase double-buffer ----------------
// C[M,N] = A[M,K] * W[N,K]^T + bias. Linear LDS [rows][32], no pad (gload_lds rule).
// Grid: x = M/BM (inner), y = N/128. XCD-bijective remap, M innermost.
// EPI 0: fp32 out.  EPI 1: bf16(relu(out)).  EPI 2: bf16(out).
template <int BM, int EPI>
__global__ __launch_bounds__(256) void gemm_bt(const unsigned short* __restrict__ A,
                                               const unsigned short* __restrict__ W,
                                               const float* __restrict__ bias,
                                               float* __restrict__ Cf,
                                               unsigned short* __restrict__ Cb,
                                               int M, int N, int K) {
  constexpr int MI = BM / 32;                      // A-frags per wave
  __shared__ __align__(16) unsigned short As[2][BM * 32];
  __shared__ __align__(16) unsigned short Bs[2][128 * 32];
  int tid = threadIdx.x;
  int lane = tid & 63, w = tid >> 6;
  int wm = (w >> 1) * (BM / 2), wn = (w & 1) * 64;
  int r = lane & 15, quad = lane >> 4;

  // XCD-aware bijective remap (m204), M innermost
  int gx = gridDim.x;
  int nwg = gx * gridDim.y;
  int lin = blockIdx.y * gx + blockIdx.x;
  int xcd = lin & 7, pos = lin >> 3;
  int qch = nwg >> 3, rch = nwg & 7;
  int wg = (xcd < rch ? xcd * (qch + 1) : rch * (qch + 1) + (xcd - rch) * qch) + pos;
  int m0 = (wg % gx) * BM;
  int n0 = (wg / gx) * 128;

  f32x4 acc[MI][4];
  #pragma unroll
  for (int i = 0; i < MI; i++)
    #pragma unroll
    for (int j = 0; j < 4; j++) acc[i][j] = (f32x4){0.f, 0.f, 0.f, 0.f};

  int lrow = lane >> 2;            // 0..15 rows per wave-chunk
  int lcol = (lane & 3) * 8;       // elem offset within 32-elem row
  auto STAGE = [&](int buf, int k0) {
    #pragma unroll
    for (int i = 0; i < BM / 64; i++) {
      int rowA = i * 64 + w * 16;
      gld_lds16(A + (size_t)(m0 + rowA + lrow) * K + k0 + lcol, &As[buf][rowA * 32]);
    }
    #pragma unroll
    for (int i = 0; i < 2; i++) {
      int rowB = i * 64 + w * 16;
      gld_lds16(W + (size_t)(n0 + rowB + lrow) * K + k0 + lcol, &Bs[buf][rowB * 32]);
    }
  };

  STAGE(0, 0);
  __syncthreads();
  int NT = K >> 5, cur = 0;
  for (int t = 0; t < NT; t++) {
    if (t + 1 < NT) STAGE(cur ^ 1, (t + 1) * 32);   // prefetch next K-step
    bf16x8 af[MI], bfr[4];
    #pragma unroll
    for (int mi = 0; mi < MI; mi++)
      af[mi] = *reinterpret_cast<const bf16x8*>(&As[cur][(wm + mi * 16 + r) * 32 + quad * 8]);
    #pragma unroll
    for (int ni = 0; ni < 4; ni++)
      bfr[ni] = *reinterpret_cast<const bf16x8*>(&Bs[cur][(wn + ni * 16 + r) * 32 + quad * 8]);
    #pragma unroll
    for (int mi = 0; mi < MI; mi++)
      #pragma unroll
      for (int ni = 0; ni < 4; ni++)
        acc[mi][ni] = __builtin_amdgcn_mfma_f32_16x16x32_bf16(af[mi], bfr[ni], acc[mi][ni], 0, 0, 0);
    __syncthreads();   // drains prefetch (vmcnt0) + guards LDS reuse
    cur ^= 1;
  }

  #pragma unroll
  for (int mi = 0; mi < MI; mi++) {
    #pragma unroll
    for (int ni = 0; ni < 4; ni++) {
      int n = n0 + wn + ni * 16 + r;          // C/D: col = lane&15
      float bv = bias[n];
      #pragma unroll
      for (int rr = 0; rr < 4; rr++) {
        int m = m0 + wm + mi * 16 + quad * 4 + rr;   // C/D: row = quad*4+reg
        float v = acc[mi][ni][rr] + bv;
        if (EPI == 0) {
          Cf[(size_t)m * N + n] = v;
        } else if (EPI == 1) {
          Cb[(size_t)m * N + n] = f2bf(fmaxf(v, 0.f));
        } else {
          Cb[(size_t)m * N + n] = f2bf(v);
        }
      }
    }
  }
}

// ---------------- fused GEMM(+bias) + residual add + layernorm ----------------
// N = 256 (= Dm) fixed. Block = 16 rows x 256 cols -> owns full LN rows.
// xf <- LN(xf + A*W^T + bias); xb <- bf16(xf). Grid: BTn/16 = 256 blocks.
template <int K>
__global__ __launch_bounds__(256) void gemm_ln(const unsigned short* __restrict__ A,
                                               const unsigned short* __restrict__ W,
                                               const float* __restrict__ bias,
                                               const float* __restrict__ gam,
                                               const float* __restrict__ bet,
                                               float* __restrict__ xf,
                                               unsigned short* __restrict__ xb) {
  constexpr int NT = K / 32;
  __shared__ __align__(16) unsigned short As[2][16 * 32];
  __shared__ __align__(16) unsigned short Bs[2][256 * 32];
  __shared__ float red0[4][16], red1[4][16];
  int tid = threadIdx.x;
  int lane = tid & 63, w = tid >> 6;
  int l15 = lane & 15, quad = lane >> 4;
  int m0 = blockIdx.x * 16;
  int wn = w * 64;                       // wave's 64-col slice
  int lrow = lane >> 2, lcol = (lane & 3) * 8;

  f32x4 acc[4];
  #pragma unroll
  for (int i = 0; i < 4; i++) acc[i] = (f32x4){0.f, 0.f, 0.f, 0.f};

  auto STAGE = [&](int buf, int k0) {
    if (w == 0)
      gld_lds16(A + (size_t)(m0 + lrow) * K + k0 + lcol, &As[buf][0]);
    #pragma unroll
    for (int i = 0; i < 4; i++) {
      int rb = (i * 4 + w) * 16;
      gld_lds16(W + (size_t)(rb + lrow) * K + k0 + lcol, &Bs[buf][rb * 32]);
    }
  };

  STAGE(0, 0);
  __syncthreads();
  int cur = 0;
  #pragma unroll 4
  for (int t = 0; t < NT; t++) {
    if (t + 1 < NT) STAGE(cur ^ 1, (t + 1) * 32);
    bf16x8 af = *reinterpret_cast<const bf16x8*>(&As[cur][l15 * 32 + quad * 8]);
    bf16x8 bfr[4];
    #pragma unroll
    for (int ni = 0; ni < 4; ni++)
      bfr[ni] = *reinterpret_cast<const bf16x8*>(&Bs[cur][(wn + ni * 16 + l15) * 32 + quad * 8]);
    #pragma unroll
    for (int ni = 0; ni < 4; ni++)
      acc[ni] = __builtin_amdgcn_mfma_f32_16x16x32_bf16(af, bfr[ni], acc[ni], 0, 0, 0);
    __syncthreads();
    cur ^= 1;
  }

  // ---- epilogue: v = acc + bias + xf (residual); then LN over the 256-wide row ----
  float v[4][4], s[4];
  #pragma unroll
  for (int rr = 0; rr < 4; rr++) s[rr] = 0.f;
  #pragma unroll
  for (int ni = 0; ni < 4; ni++) {
    int n = wn + ni * 16 + l15;
    float bv = bias[n];
    #pragma unroll
    for (int rr = 0; rr < 4; rr++) {
      int m = m0 + quad * 4 + rr;
      float x = acc[ni][rr] + bv + xf[(size_t)m * Dm + n];
      v[ni][rr] = x;
      s[rr] += x;
    }
  }
  #pragma unroll
  for (int rr = 0; rr < 4; rr++) {
    #pragma unroll
    for (int o = 8; o > 0; o >>= 1) s[rr] += __shfl_xor(s[rr], o);
  }
  if (l15 == 0) {
    #pragma unroll
    for (int rr = 0; rr < 4; rr++) red0[w][quad * 4 + rr] = s[rr];
  }
  __syncthreads();
  float mean[4], vs[4];
  #pragma unroll
  for (int rr = 0; rr < 4; rr++) {
    int rw = quad * 4 + rr;
    mean[rr] = (red0[0][rw] + red0[1][rw] + red0[2][rw] + red0[3][rw]) * (1.f / 256.f);
    vs[rr] = 0.f;
  }
  #pragma unroll
  for (int ni = 0; ni < 4; ni++)
    #pragma unroll
    for (int rr = 0; rr < 4; rr++) {
      float df = v[ni][rr] - mean[rr];
      vs[rr] += df * df;
    }
  #pragma unroll
  for (int rr = 0; rr < 4; rr++) {
    #pragma unroll
    for (int o = 8; o > 0; o >>= 1) vs[rr] += __shfl_xor(vs[rr], o);
  }
  if (l15 == 0) {
    #pragma unroll
    for (int rr = 0; rr < 4; rr++) red1[w][quad * 4 + rr] = vs[rr];
  }
  __syncthreads();
  #pragma unroll
  for (int rr = 0; rr < 4; rr++) {
    int rw = quad * 4 + rr;
    float var = (red1[0][rw] + red1[1][rw] + red1[2][rw] + red1[3][rw]) * (1.f / 256.f);
    vs[rr] = rsqrtf(var + 1e-5f);
  }
  #pragma unroll
  for (int ni = 0; ni < 4; ni++) {
    int n = wn + ni * 16 + l15;
    float g = gam[n], be = bet[n];
    #pragma unroll
    for (int rr = 0; rr < 4; rr++) {
      int m = m0 + quad * 4 + rr;
      float y = (v[ni][rr] - mean[rr]) * vs[rr] * g + be;
      xf[(size_t)m * Dm + n] = y;
      xb[(size_t)m * Dm + n] = f2bf(y);
    }
  }
}

extern "C" void kernel_launch(void* const* d_in, const int* in_sizes, int n_in,
                              void* d_out, int out_size, void* d_ws, size_t ws_size,
                              hipStream_t stream) {
  (void)in_sizes; (void)n_in; (void)out_size; (void)ws_size;
  const int* tokens = (const int*)d_in[0];
  const float* emb = (const float*)d_in[1];
  const float* qkv_w = (const float*)d_in[2];
  const float* qkv_b = (const float*)d_in[3];
  const float* fc_w = (const float*)d_in[4];
  const float* fc_b = (const float*)d_in[5];
  const float* ln1_s = (const float*)d_in[6];
  const float* ln1_b = (const float*)d_in[7];
  const float* w1 = (const float*)d_in[8];
  const float* b1 = (const float*)d_in[9];
  const float* w2 = (const float*)d_in[10];
  const float* b2 = (const float*)d_in[11];
  const float* ln2_s = (const float*)d_in[12];
  const float* ln2_b = (const float*)d_in[13];
  const float* lnf_s = (const float*)d_in[14];
  const float* lnf_b = (const float*)d_in[15];
  const float* out_w = (const float*)d_in[16];
  const float* out_b = (const float*)d_in[17];
  float* logits = (float*)d_out;

  char* p = (char*)d_ws;
  auto carve = [&](size_t bytes) {
    char* r = p;
    p += (bytes + 255) & ~(size_t)255;
    return r;
  };
  float* xf = (float*)carve((size_t)BTn * Dm * 4);
  unsigned short* xb = (unsigned short*)carve((size_t)BTn * Dm * 2);
  unsigned short* qkvb = (unsigned short*)carve((size_t)BTn * 768 * 2);
  unsigned short* obb = (unsigned short*)carve((size_t)BTn * Dm * 2);
  unsigned short* hb = (unsigned short*)carve((size_t)BTn * DFFn * 2);
  unsigned short* wqkvb = (unsigned short*)carve((size_t)Ln * 768 * Dm * 2);
  unsigned short* wfcb = (unsigned short*)carve((size_t)Ln * Dm * Dm * 2);
  unsigned short* w1b = (unsigned short*)carve((size_t)Ln * DFFn * Dm * 2);
  unsigned short* w2b = (unsigned short*)carve((size_t)Ln * Dm * DFFn * 2);
  unsigned short* outwb = (unsigned short*)carve((size_t)Vn * Dm * 2);

  // merged weight conversion (5 tensors, one launch); offsets in vec4 units
  {
    int c0 = Ln * 768 * Dm / 4;
    int c1 = c0 + Ln * Dm * Dm / 4;
    int c2 = c1 + Ln * DFFn * Dm / 4;
    int c3 = c2 + Ln * Dm * DFFn / 4;
    int c4 = c3 + Vn * Dm / 4;
    cvt_all<<<dim3((c4 + 255) / 256), dim3(256), 0, stream>>>(
        qkv_w, wqkvb, fc_w, wfcb, w1, w1b, w2, w2b, out_w, outwb, c0, c1, c2, c3, c4);
  }

  embed_pos<<<dim3(BTn), dim3(256), 0, stream>>>(tokens, emb, xf, xb);

  for (int l = 0; l < Ln; l++) {
    gemm_bt<64, 2><<<dim3(BTn / 64, 768 / 128), dim3(256), 0, stream>>>(
        xb, wqkvb + (size_t)l * 768 * Dm, qkv_b + l * 768, nullptr, qkvb, BTn, 768, Dm);
    attn_mfma<<<dim3(Tn / 64, 2 * NHn), dim3(256), 0, stream>>>(qkvb, obb);
    gemm_ln<256><<<dim3(BTn / 16), dim3(256), 0, stream>>>(
        obb, wfcb + (size_t)l * Dm * Dm, fc_b + l * Dm, ln1_s + l * Dm, ln1_b + l * Dm, xf, xb);
    gemm_bt<128, 1><<<dim3(BTn / 128, DFFn / 128), dim3(256), 0, stream>>>(
        xb, w1b + (size_t)l * DFFn * Dm, b1 + l * DFFn, nullptr, hb, BTn, DFFn, Dm);
    gemm_ln<1024><<<dim3(BTn / 16), dim3(256), 0, stream>>>(
        hb, w2b + (size_t)l * Dm * DFFn, b2 + l * Dm, ln2_s + l * Dm, ln2_b + l * Dm, xf, xb);
  }
  add_ln<<<dim3(BTn), dim3(256), 0, stream>>>(nullptr, lnf_s, lnf_b, xf, xb);

  gemm_bt<128, 0><<<dim3(BTn / 128, Vn / 128), dim3(256), 0, stream>>>(
      xb, outwb, out_b, logits, nullptr, BTn, Vn, Dm);
}